// Round 6
// baseline (221.416 us; speedup 1.0000x reference)
//
#include <hip/hip_runtime.h>
#include <hip/hip_bf16.h>
#include <stdint.h>

#define NSUB 16

typedef short  bf16x8 __attribute__((ext_vector_type(8)));
typedef float  f32x4  __attribute__((ext_vector_type(4)));
typedef unsigned int u32x4 __attribute__((ext_vector_type(4)));

__device__ __forceinline__ float gelu_exact(float x){
  return 0.5f * x * (1.0f + erff(x * 0.70710678118654752440f));
}

// tanh-form GELU via sigmoid identity: gelu(x) = x * sigmoid(1.59577*(x+0.044715x^3))
// = x / (1 + exp2(-2.3022084 * x * (1+0.044715x^2))).  |err| <= ~5e-4.
__device__ __forceinline__ float gelu_fast(float x){
  float xx = x * x;
  float m  = fmaf(0.044715f, xx, 1.0f);
  float a  = x * m * -2.3022084f;
  float e  = __builtin_amdgcn_exp2f(a);
  float r  = __builtin_amdgcn_rcpf(e + 1.0f);
  return x * r;
}

__device__ __forceinline__ unsigned short f2bf(float f){
  union { float f; uint32_t u; } v; v.f = f;
  uint32_t u = v.u;
  return (unsigned short)((u + 0x7FFFu + ((u >> 16) & 1u)) >> 16);
}

__device__ __forceinline__ unsigned int pk2(float lo, float hi){
  union { __hip_bfloat162 b; unsigned int u; } c;
  c.b = __float22bfloat162_rn(make_float2(lo, hi));
  return c.u;
}

__device__ __forceinline__ bf16x8 as_bf(u32x4 v){
  union { u32x4 u; bf16x8 b; } c; c.u = v; return c.b;
}

__device__ __forceinline__ float bflo(unsigned int u){
  union { unsigned int u; float f; } c; c.u = u << 16; return c.f;
}
__device__ __forceinline__ float bfhi(unsigned int u){
  union { unsigned int u; float f; } c; c.u = u & 0xffff0000u; return c.f;
}

// ---------------- weights -> bf16, MFMA-B-fragment order, into d_ws ----------
// flat = ((ks*NT + nn)*64 + lane)*8 + j ; lane = ((k>>3)&3)*16 + (n&15), j = k&7
__global__ __launch_bounds__(256) void wconv_kernel(
    const float* __restrict__ W1, const float* __restrict__ W2, const float* __restrict__ W3,
    unsigned short* __restrict__ W1f, unsigned short* __restrict__ W2f, unsigned short* __restrict__ W3f){
  int t = blockIdx.x * 256 + threadIdx.x;
  if (t < 131072){                       // W1: K=512, N=256
    int n = t >> 9, k = t & 511;
    int lane = ((k >> 3) & 3) * 16 + (n & 15);
    int idx = (((k >> 5) * 16 + (n >> 4)) * 64 + lane) * 8 + (k & 7);
    W1f[idx] = f2bf(W1[k*256 + n]);
  } else if (t < 163840){                // W2: K=256, N=128
    int i = t - 131072; int n = i >> 8, k = i & 255;
    int lane = ((k >> 3) & 3) * 16 + (n & 15);
    int idx = (((k >> 5) * 8 + (n >> 4)) * 64 + lane) * 8 + (k & 7);
    W2f[idx] = f2bf(W2[k*128 + n]);
  } else if (t < 165888){                // W3: K=128, N=16
    int i = t - 163840; int n = i >> 7, k = i & 127;
    int lane = ((k >> 3) & 3) * 16 + n;
    int idx = ((k >> 5) * 64 + lane) * 8 + (k & 7);
    W3f[idx] = f2bf(W3[k*16 + n]);
  }
}

// ---------------- fused LN + 3-GEMM MLP, 16 rows/block ----------------
// 256 thr / 4 waves, grid 8192, LDS 16KB -> 8 blocks/CU (occupancy is the lever).
// X [16][512]bf16 swizzled (16KB); H1 (8KB) overlays X[0:8K] after GEMM1;
// H2 (4KB) overlays X[8K:12K]. 4 barriers. LN = own pre-barrier phase (R4 style).
__global__ __launch_bounds__(256) void fused_kernel(
    const float* __restrict__ x, const int* __restrict__ groups,
    const float* __restrict__ gammas, const float* __restrict__ betas,
    const unsigned short* __restrict__ W1f, const float* __restrict__ b1,
    const unsigned short* __restrict__ W2f, const float* __restrict__ b2,
    const unsigned short* __restrict__ W3f, const float* __restrict__ b3,
    float* __restrict__ ln_out, float* __restrict__ out2){
  __shared__ __align__(16) uint8_t smem[16384];
  constexpr int OFF_H2 = 8192;

  const int tid  = threadIdx.x;
  const int wave = tid >> 6;
  const int lane = tid & 63;
  const int l15  = lane & 15;
  const int g4   = lane >> 4;
  const int row0 = blockIdx.x * 16;

  // ---- phase 0: stage x -> LDS bf16 (swizzled) + f32 row stats ----
  const int sr  = tid >> 4;           // row 0..15  (16 threads/row)
  const int sc  = tid & 15;           // 8-float column group
  const int swz = (sr & 7) << 4;
  uint8_t* xrow = smem + sr*1024;
  const float* xg = x + (size_t)(row0 + sr)*512 + sc*8;

  int gi   = groups[row0 + sr];
  int gidx = ((unsigned)gi < (unsigned)NSUB) ? gi : NSUB;

  float s = 0.f, q = 0.f;
  #pragma unroll
  for (int c = 0; c < 4; ++c){
    f32x4 v0 = *(const f32x4*)(xg + c*128);
    f32x4 v1 = *(const f32x4*)(xg + c*128 + 4);
    s += v0.x + v0.y + v0.z + v0.w + v1.x + v1.y + v1.z + v1.w;
    q += v0.x*v0.x + v0.y*v0.y + v0.z*v0.z + v0.w*v0.w
       + v1.x*v1.x + v1.y*v1.y + v1.z*v1.z + v1.w*v1.w;
    u32x4 pw;
    pw.x = pk2(v0.x, v0.y); pw.y = pk2(v0.z, v0.w);
    pw.z = pk2(v1.x, v1.y); pw.w = pk2(v1.z, v1.w);
    *(u32x4*)(xrow + ((c*256 + sc*16) ^ swz)) = pw;
  }
  s += __shfl_xor(s, 1); s += __shfl_xor(s, 2);
  s += __shfl_xor(s, 4); s += __shfl_xor(s, 8);
  q += __shfl_xor(q, 1); q += __shfl_xor(q, 2);
  q += __shfl_xor(q, 4); q += __shfl_xor(q, 8);
  float mu  = s * (1.0f/512.0f);
  float var = q * (1.0f/512.0f) - mu*mu;
  float rs  = rsqrtf(var + 1e-5f);
  float nmr = -mu * rs;

  // W1 ring-2 prologue FIRST: oldest in vmcnt queue so GEMM1's first wait
  // doesn't drain the LN loads/stores issued below.
  u32x4 braw[2][4];
  #pragma unroll
  for (int n = 0; n < 4; ++n)
    braw[0][n] = *(const u32x4*)(W1f + (size_t)(((wave*4 + n)*64 + lane)*8));

  // bias preload (L2)
  float b1v[4], b2v[2], b3v;
  #pragma unroll
  for (int n = 0; n < 4; ++n) b1v[n] = b1[wave*64 + n*16 + l15];
  #pragma unroll
  for (int n = 0; n < 2; ++n) b2v[n] = b2[wave*32 + n*16 + l15];
  b3v = b3[l15];

  // ---- phase 1: LN output (reads own thread's LDS writes; stores drain under GEMM1) ----
  {
    const float* gpr = gammas + (size_t)gidx*512 + sc*8;
    const float* bpr = betas  + (size_t)gidx*512 + sc*8;
    float* op = ln_out + (size_t)(row0 + sr)*512 + sc*8;
    #pragma unroll
    for (int c = 0; c < 4; ++c){
      u32x4 pw = *(const u32x4*)(xrow + ((c*256 + sc*16) ^ swz));
      f32x4 g0 = *(const f32x4*)(gpr + c*128);
      f32x4 g1 = *(const f32x4*)(gpr + c*128 + 4);
      f32x4 e0 = *(const f32x4*)(bpr + c*128);
      f32x4 e1 = *(const f32x4*)(bpr + c*128 + 4);
      f32x4 o0, o1;
      o0.x = fmaf(fmaf(bflo(pw.x), rs, nmr), g0.x, e0.x);
      o0.y = fmaf(fmaf(bfhi(pw.x), rs, nmr), g0.y, e0.y);
      o0.z = fmaf(fmaf(bflo(pw.y), rs, nmr), g0.z, e0.z);
      o0.w = fmaf(fmaf(bfhi(pw.y), rs, nmr), g0.w, e0.w);
      o1.x = fmaf(fmaf(bflo(pw.z), rs, nmr), g1.x, e1.x);
      o1.y = fmaf(fmaf(bfhi(pw.z), rs, nmr), g1.y, e1.y);
      o1.z = fmaf(fmaf(bflo(pw.w), rs, nmr), g1.z, e1.z);
      o1.w = fmaf(fmaf(bfhi(pw.w), rs, nmr), g1.w, e1.w);
      *(f32x4*)(op + c*128)     = o0;
      *(f32x4*)(op + c*128 + 4) = o1;
    }
  }

  // GEMM1 A-fragment bases: row = l15; swizzle bit6 folded via kx.
  int baseA[2];
  {
    int row = l15;
    int sw  = (row & 7) << 4;
    int bse = row*1024 + ((g4*16) ^ (sw & 0x30));
    int kx  = (row >> 2) & 1;
    baseA[0] = bse + ((0 ^ kx) << 6);
    baseA[1] = bse + ((1 ^ kx) << 6);
  }

  __syncthreads();   // X fully staged

  // ---- GEMM1: 16x256, K=512, zero intra-GEMM barriers ----
  f32x4 acc1[4] = {};
  #pragma unroll
  for (int g = 0; g < 16; ++g){
    if (g < 15){
      #pragma unroll
      for (int n = 0; n < 4; ++n)
        braw[(g+1)&1][n] = *(const u32x4*)(W1f + (size_t)((((g+1)*16 + wave*4 + n)*64 + lane)*8));
    }
    bf16x8 a = *(const bf16x8*)(smem + baseA[g & 1] + (g >> 1)*128);
    #pragma unroll
    for (int n = 0; n < 4; ++n)
      acc1[n] = __builtin_amdgcn_mfma_f32_16x16x32_bf16(a, as_bf(braw[g & 1][n]), acc1[n], 0, 0, 0);
  }

  // GEMM2 ring-4 prologue: 3 steps in flight before epilogue-1's VALU
  u32x4 b2raw[4][2];
  #pragma unroll
  for (int p = 0; p < 3; ++p)
    #pragma unroll
    for (int n = 0; n < 2; ++n)
      b2raw[p][n] = *(const u32x4*)(W2f + (size_t)(((p*8 + wave*2 + n)*64 + lane)*8));

  __syncthreads();   // all X reads done; H1 may overlay X[0:8K]

  // ---- epilogue 1: bias + GELU -> H1 bf16 swizzled at smem[0:8K] ----
  #pragma unroll
  for (int n = 0; n < 4; ++n){
    #pragma unroll
    for (int r = 0; r < 4; ++r){
      int row = g4*4 + r;
      int col = wave*64 + n*16 + l15;
      float v = gelu_fast(acc1[n][r] + b1v[n]);
      *(unsigned short*)(smem + row*512 + ((col*2) ^ ((row & 7) << 4))) = f2bf(v);
    }
  }
  __syncthreads();   // H1 ready

  // ---- GEMM2: 16x128, K=256, ring-4 W prefetch 3 ahead ----
  int baseH[2];
  {
    int row = l15;
    int sw  = (row & 7) << 4;
    int bse = row*512 + ((g4*16) ^ (sw & 0x30));
    int kx  = (row >> 2) & 1;
    baseH[0] = bse + ((0 ^ kx) << 6);
    baseH[1] = bse + ((1 ^ kx) << 6);
  }
  f32x4 acc2[2] = {};
  #pragma unroll
  for (int g = 0; g < 8; ++g){
    if (g < 5){
      #pragma unroll
      for (int n = 0; n < 2; ++n)
        b2raw[(g+3)&3][n] = *(const u32x4*)(W2f + (size_t)((((g+3)*8 + wave*2 + n)*64 + lane)*8));
    }
    bf16x8 a = *(const bf16x8*)(smem + baseH[g & 1] + (g >> 1)*128);
    #pragma unroll
    for (int n = 0; n < 2; ++n)
      acc2[n] = __builtin_amdgcn_mfma_f32_16x16x32_bf16(a, as_bf(b2raw[g & 3][n]), acc2[n], 0, 0, 0);
  }

  // W3 fragment prefetch (covered by epilogue-2 VALU)
  u32x4 b3raw[4];
  #pragma unroll
  for (int ks = 0; ks < 4; ++ks)
    b3raw[ks] = *(const u32x4*)(W3f + (size_t)((ks*64 + lane)*8));

  // ---- epilogue 2: bias + GELU -> H2 bf16 swizzled at smem[8K:12K] ----
  #pragma unroll
  for (int n = 0; n < 2; ++n){
    #pragma unroll
    for (int r = 0; r < 4; ++r){
      int row = g4*4 + r;
      int col = wave*32 + n*16 + l15;
      float v = gelu_fast(acc2[n][r] + b2v[n]);
      *(unsigned short*)(smem + OFF_H2 + row*256 + ((col*2) ^ ((row & 7) << 4))) = f2bf(v);
    }
  }
  __syncthreads();   // H2 ready

  // ---- GEMM3: 16x16, K=128 (all waves compute; wave 0 stores) ----
  int baseG[2];
  {
    int row = l15;
    int sw  = (row & 7) << 4;
    int bse = OFF_H2 + row*256 + ((g4*16) ^ (sw & 0x30));
    int kx  = (row >> 2) & 1;
    baseG[0] = bse + ((0 ^ kx) << 6);
    baseG[1] = bse + ((1 ^ kx) << 6);
  }
  f32x4 acc3 = {};
  #pragma unroll
  for (int ks = 0; ks < 4; ++ks){
    bf16x8 a = *(const bf16x8*)(smem + baseG[ks & 1] + (ks >> 1)*128);
    acc3 = __builtin_amdgcn_mfma_f32_16x16x32_bf16(a, as_bf(b3raw[ks]), acc3, 0, 0, 0);
  }
  if (wave == 0){
    #pragma unroll
    for (int r = 0; r < 4; ++r){
      int grow = row0 + g4*4 + r;
      out2[(size_t)grow*16 + l15] = acc3[r] + b3v;
    }
  }
}

// ---------------- fallback path (ws too small): naive MLP + standalone LN ----------------
__global__ __launch_bounds__(256) void ln_kernel(
    const float* __restrict__ x, const int* __restrict__ groups,
    const float* __restrict__ gammas, const float* __restrict__ betas,
    float* __restrict__ out){
  int row  = blockIdx.x * 4 + (threadIdx.x >> 6);
  int lane = threadIdx.x & 63;
  const float4* xr = (const float4*)(x + (size_t)row * 512);
  float4 a = xr[lane];
  float4 b = xr[lane + 64];
  float s = a.x + a.y + a.z + a.w + b.x + b.y + b.z + b.w;
  float q = a.x*a.x + a.y*a.y + a.z*a.z + a.w*a.w
          + b.x*b.x + b.y*b.y + b.z*b.z + b.w*b.w;
  #pragma unroll
  for (int o = 32; o > 0; o >>= 1){
    s += __shfl_xor(s, o);
    q += __shfl_xor(q, o);
  }
  float mu  = s * (1.0f/512.0f);
  float var = q * (1.0f/512.0f) - mu*mu;
  float rsq = rsqrtf(var + 1e-5f);
  int gi = groups[row];
  int idx = ((unsigned)gi < (unsigned)NSUB) ? gi : NSUB;
  const float4* gr = (const float4*)(gammas + (size_t)idx * 512);
  const float4* br = (const float4*)(betas  + (size_t)idx * 512);
  float4 g0 = gr[lane], g1 = gr[lane + 64];
  float4 e0 = br[lane], e1 = br[lane + 64];
  float4 o0, o1;
  o0.x = (a.x - mu)*rsq*g0.x + e0.x; o0.y = (a.y - mu)*rsq*g0.y + e0.y;
  o0.z = (a.z - mu)*rsq*g0.z + e0.z; o0.w = (a.w - mu)*rsq*g0.w + e0.w;
  o1.x = (b.x - mu)*rsq*g1.x + e1.x; o1.y = (b.y - mu)*rsq*g1.y + e1.y;
  o1.z = (b.z - mu)*rsq*g1.z + e1.z; o1.w = (b.w - mu)*rsq*g1.w + e1.w;
  float4* orow = (float4*)(out + (size_t)row * 512);
  orow[lane]      = o0;
  orow[lane + 64] = o1;
}

__global__ __launch_bounds__(256) void mlp_naive(
    const float* __restrict__ x,
    const float* __restrict__ W1, const float* __restrict__ b1,
    const float* __restrict__ W2, const float* __restrict__ b2,
    const float* __restrict__ W3, const float* __restrict__ b3,
    float* __restrict__ out2){
  __shared__ float xr[512];
  __shared__ float h1[256];
  __shared__ float h2[128];
  int row = blockIdx.x, t = threadIdx.x;
  xr[t]       = x[(size_t)row*512 + t];
  xr[t + 256] = x[(size_t)row*512 + t + 256];
  __syncthreads();
  {
    float s = 0.f;
    for (int k = 0; k < 512; ++k) s += xr[k] * W1[k*256 + t];
    h1[t] = gelu_exact(s + b1[t]);
  }
  __syncthreads();
  if (t < 128){
    float s = 0.f;
    for (int k = 0; k < 256; ++k) s += h1[k] * W2[k*128 + t];
    h2[t] = gelu_exact(s + b2[t]);
  }
  __syncthreads();
  if (t < 16){
    float s = 0.f;
    for (int k = 0; k < 128; ++k) s += h2[k] * W3[k*16 + t];
    out2[(size_t)row*16 + t] = s + b3[t];
  }
}

extern "C" void kernel_launch(void* const* d_in, const int* in_sizes, int n_in,
                              void* d_out, int out_size, void* d_ws, size_t ws_size,
                              hipStream_t stream){
  const float* x      = (const float*)d_in[0];
  const int*   groups = (const int*)d_in[1];
  const float* gammas = (const float*)d_in[2];
  const float* betas  = (const float*)d_in[3];
  const float* W1 = (const float*)d_in[4];
  const float* b1 = (const float*)d_in[5];
  const float* W2 = (const float*)d_in[6];
  const float* b2 = (const float*)d_in[7];
  const float* W3 = (const float*)d_in[8];
  const float* b3 = (const float*)d_in[9];
  float* out  = (float*)d_out;
  const int B = in_sizes[0] / 512;
  float* out2 = out + (size_t)B * 512;

  const int n_u16 = 131072 + 32768 + 2048;
  const size_t ws_need = (size_t)n_u16 * sizeof(unsigned short);
  if (ws_size >= ws_need){
    unsigned short* W1f = (unsigned short*)d_ws;
    unsigned short* W2f = W1f + 131072;
    unsigned short* W3f = W2f + 32768;
    wconv_kernel<<<(n_u16 + 255)/256, 256, 0, stream>>>(W1, W2, W3, W1f, W2f, W3f);
    fused_kernel<<<B/16, 256, 0, stream>>>(x, groups, gammas, betas,
                                           W1f, b1, W2f, b2, W3f, b3, out, out2);
  } else {
    mlp_naive<<<B, 256, 0, stream>>>(x, W1, b1, W2, b2, W3, b3, out2);
    ln_kernel<<<B/4, 256, 0, stream>>>(x, groups, gammas, betas, out);
  }
}

// Round 7
// 155.495 us; speedup vs baseline: 1.4239x; 1.4239x over previous
//
#include <hip/hip_runtime.h>
#include <hip/hip_bf16.h>
#include <stdint.h>

#define NSUB 16

typedef short  bf16x8 __attribute__((ext_vector_type(8)));
typedef float  f32x4  __attribute__((ext_vector_type(4)));
typedef unsigned int u32x4 __attribute__((ext_vector_type(4)));

__device__ __forceinline__ float gelu_exact(float x){
  return 0.5f * x * (1.0f + erff(x * 0.70710678118654752440f));
}

// tanh-form GELU via sigmoid identity; |err| <= ~5e-4 (verified R6: absmax unchanged)
__device__ __forceinline__ float gelu_fast(float x){
  float xx = x * x;
  float m  = fmaf(0.044715f, xx, 1.0f);
  float a  = x * m * -2.3022084f;
  float e  = __builtin_amdgcn_exp2f(a);
  float r  = __builtin_amdgcn_rcpf(e + 1.0f);
  return x * r;
}

__device__ __forceinline__ unsigned short f2bf(float f){
  union { float f; uint32_t u; } v; v.f = f;
  uint32_t u = v.u;
  return (unsigned short)((u + 0x7FFFu + ((u >> 16) & 1u)) >> 16);
}

__device__ __forceinline__ unsigned int pk2(float lo, float hi){
  union { __hip_bfloat162 b; unsigned int u; } c;
  c.b = __float22bfloat162_rn(make_float2(lo, hi));
  return c.u;
}

__device__ __forceinline__ bf16x8 as_bf(u32x4 v){
  union { u32x4 u; bf16x8 b; } c; c.u = v; return c.b;
}

__device__ __forceinline__ float bflo(unsigned int u){
  union { unsigned int u; float f; } c; c.u = u << 16; return c.f;
}
__device__ __forceinline__ float bfhi(unsigned int u){
  union { unsigned int u; float f; } c; c.u = u & 0xffff0000u; return c.f;
}

// ---------------- weights -> bf16, MFMA-B-fragment order, into d_ws ----------
// flat = ((ks*NT + nn)*64 + lane)*8 + j ; lane = ((k>>3)&3)*16 + (n&15), j = k&7
__global__ __launch_bounds__(256) void wconv_kernel(
    const float* __restrict__ W1, const float* __restrict__ W2, const float* __restrict__ W3,
    unsigned short* __restrict__ W1f, unsigned short* __restrict__ W2f, unsigned short* __restrict__ W3f){
  int t = blockIdx.x * 256 + threadIdx.x;
  if (t < 131072){                       // W1: K=512, N=256 (nn 0..15)
    int n = t >> 9, k = t & 511;
    int lane = ((k >> 3) & 3) * 16 + (n & 15);
    int idx = (((k >> 5) * 16 + (n >> 4)) * 64 + lane) * 8 + (k & 7);
    W1f[idx] = f2bf(W1[k*256 + n]);
  } else if (t < 163840){                // W2: K=256, N=128 (nn 0..7)
    int i = t - 131072; int n = i >> 8, k = i & 255;
    int lane = ((k >> 3) & 3) * 16 + (n & 15);
    int idx = (((k >> 5) * 8 + (n >> 4)) * 64 + lane) * 8 + (k & 7);
    W2f[idx] = f2bf(W2[k*128 + n]);
  } else if (t < 165888){                // W3: K=128, N=16
    int i = t - 163840; int n = i >> 7, k = i & 127;
    int lane = ((k >> 3) & 3) * 16 + n;
    int idx = ((k >> 5) * 64 + lane) * 8 + (k & 7);
    W3f[idx] = f2bf(W3[k*16 + n]);
  }
}

// ---------------- fused LN + 3-GEMM MLP, 64 rows/block, 8 waves ----------------
// 512 thr, grid 2048. W L2 traffic = 2048 x 324KB = 664MB (best measured tier).
// Each wave owns a 32-col N-slice of GEMM1 (acc[4][2]) and 16-col of GEMM2.
// Ring-4 W prefetch issued BEFORE the LN phase (oldest in vmcnt queue).
// LDS 64KB: X [64][512]bf16 swz; H1 (32KB) overlays X[0:32K]; H2 (16KB) at 32K.
__global__ __launch_bounds__(512, 4) void fused_kernel(
    const float* __restrict__ x, const int* __restrict__ groups,
    const float* __restrict__ gammas, const float* __restrict__ betas,
    const unsigned short* __restrict__ W1f, const float* __restrict__ b1,
    const unsigned short* __restrict__ W2f, const float* __restrict__ b2,
    const unsigned short* __restrict__ W3f, const float* __restrict__ b3,
    float* __restrict__ ln_out, float* __restrict__ out2){
  __shared__ __align__(16) uint8_t smem[65536];
  constexpr int OFF_H2 = 32768;

  const int tid  = threadIdx.x;
  const int wave = tid >> 6;        // 0..7
  const int lane = tid & 63;
  const int l15  = lane & 15;
  const int g4   = lane >> 4;
  const int row0 = blockIdx.x * 64;

  // ---- phase 0: stage x -> LDS bf16 (swizzled) + f32 row stats ----
  const int sr  = tid >> 3;          // row 0..63 (8 threads/row)
  const int sc  = tid & 7;           // 8-float column group
  const int swz = (sr & 7) << 4;
  const int wb  = (sc*16) ^ swz;
  uint8_t* xrow = smem + sr*1024;
  const float* xg = x + (size_t)(row0 + sr)*512 + sc*8;

  int gi   = groups[row0 + sr];
  int gidx = ((unsigned)gi < (unsigned)NSUB) ? gi : NSUB;

  float s = 0.f, q = 0.f;
  #pragma unroll
  for (int t = 0; t < 8; ++t){
    f32x4 v0 = *(const f32x4*)(xg + t*64);
    f32x4 v1 = *(const f32x4*)(xg + t*64 + 4);
    s += v0.x + v0.y + v0.z + v0.w + v1.x + v1.y + v1.z + v1.w;
    q += v0.x*v0.x + v0.y*v0.y + v0.z*v0.z + v0.w*v0.w
       + v1.x*v1.x + v1.y*v1.y + v1.z*v1.z + v1.w*v1.w;
    u32x4 pw;
    pw.x = pk2(v0.x, v0.y); pw.y = pk2(v0.z, v0.w);
    pw.z = pk2(v1.x, v1.y); pw.w = pk2(v1.z, v1.w);
    *(u32x4*)(xrow + t*128 + wb) = pw;
  }
  s += __shfl_xor(s, 1); s += __shfl_xor(s, 2); s += __shfl_xor(s, 4);
  q += __shfl_xor(q, 1); q += __shfl_xor(q, 2); q += __shfl_xor(q, 4);
  float mu  = s * (1.0f/512.0f);
  float var = q * (1.0f/512.0f) - mu*mu;
  float rs  = rsqrtf(var + 1e-5f);
  float nmr = -mu * rs;

  // W1 ring-4 prologue FIRST (steps 0..2): oldest in vmcnt queue, completes
  // under the LN phase. Per wave: nn = wave*2 + n (n=0,1).
  u32x4 braw[4][2];
  #pragma unroll
  for (int p = 0; p < 3; ++p)
    #pragma unroll
    for (int n = 0; n < 2; ++n)
      braw[p][n] = *(const u32x4*)(W1f + (size_t)(((p*16 + wave*2 + n)*64 + lane)*8));

  // bias preload (L2)
  float b1v[2];
  #pragma unroll
  for (int n = 0; n < 2; ++n) b1v[n] = b1[wave*32 + n*16 + l15];
  float b2v = b2[wave*16 + l15];
  float b3v = b3[l15];

  // ---- phase 1: LN output (reads own thread's LDS writes; stores drain under GEMM1) ----
  {
    const float* gpr = gammas + (size_t)gidx*512 + sc*8;
    const float* bpr = betas  + (size_t)gidx*512 + sc*8;
    float* op = ln_out + (size_t)(row0 + sr)*512 + sc*8;
    #pragma unroll
    for (int t = 0; t < 8; ++t){
      u32x4 pw = *(const u32x4*)(xrow + t*128 + wb);
      f32x4 g0 = *(const f32x4*)(gpr + t*64);
      f32x4 g1 = *(const f32x4*)(gpr + t*64 + 4);
      f32x4 e0 = *(const f32x4*)(bpr + t*64);
      f32x4 e1 = *(const f32x4*)(bpr + t*64 + 4);
      f32x4 o0, o1;
      o0.x = fmaf(fmaf(bflo(pw.x), rs, nmr), g0.x, e0.x);
      o0.y = fmaf(fmaf(bfhi(pw.x), rs, nmr), g0.y, e0.y);
      o0.z = fmaf(fmaf(bflo(pw.y), rs, nmr), g0.z, e0.z);
      o0.w = fmaf(fmaf(bfhi(pw.y), rs, nmr), g0.w, e0.w);
      o1.x = fmaf(fmaf(bflo(pw.z), rs, nmr), g1.x, e1.x);
      o1.y = fmaf(fmaf(bfhi(pw.z), rs, nmr), g1.y, e1.y);
      o1.z = fmaf(fmaf(bflo(pw.w), rs, nmr), g1.z, e1.z);
      o1.w = fmaf(fmaf(bfhi(pw.w), rs, nmr), g1.w, e1.w);
      *(f32x4*)(op + t*64)     = o0;
      *(f32x4*)(op + t*64 + 4) = o1;
    }
  }

  // GEMM1 A-fragment bases (swizzle bits 4-5 folded; bit 6 via kx toggle)
  int baseA[4][2];
  #pragma unroll
  for (int m = 0; m < 4; ++m){
    int row = m*16 + l15;
    int sw  = (row & 7) << 4;
    int bse = row*1024 + ((g4*16) ^ (sw & 0x30));
    int kx  = (row >> 2) & 1;
    baseA[m][0] = bse + ((0 ^ kx) << 6);
    baseA[m][1] = bse + ((1 ^ kx) << 6);
  }

  __syncthreads();   // X fully staged

  // ---- GEMM1: 64x256, K=512; per wave N=32 (acc[4][2]); ring-4, 3 ahead ----
  f32x4 acc1[4][2] = {};
  #pragma unroll
  for (int g = 0; g < 16; ++g){
    if (g < 13){
      #pragma unroll
      for (int n = 0; n < 2; ++n)
        braw[(g+3)&3][n] = *(const u32x4*)(W1f + (size_t)((((g+3)*16 + wave*2 + n)*64 + lane)*8));
    }
    bf16x8 a[4];
    #pragma unroll
    for (int m = 0; m < 4; ++m)
      a[m] = *(const bf16x8*)(smem + baseA[m][g & 1] + (g >> 1)*128);
    #pragma unroll
    for (int m = 0; m < 4; ++m)
      #pragma unroll
      for (int n = 0; n < 2; ++n)
        acc1[m][n] = __builtin_amdgcn_mfma_f32_16x16x32_bf16(a[m], as_bf(braw[g & 3][n]), acc1[m][n], 0, 0, 0);
  }

  // GEMM2 ring-4 prologue (per wave nn = wave): issue before barrier+epilogue
  u32x4 b2raw[4];
  #pragma unroll
  for (int p = 0; p < 3; ++p)
    b2raw[p] = *(const u32x4*)(W2f + (size_t)(((p*8 + wave)*64 + lane)*8));

  __syncthreads();   // all X reads done; H1 may overlay X[0:32K]

  // ---- epilogue 1: bias + GELU -> H1 bf16 swizzled at smem[0:32K] ----
  #pragma unroll
  for (int n = 0; n < 2; ++n){
    #pragma unroll
    for (int m = 0; m < 4; ++m){
      #pragma unroll
      for (int r = 0; r < 4; ++r){
        int row = m*16 + g4*4 + r;
        int col = wave*32 + n*16 + l15;
        float v = gelu_fast(acc1[m][n][r] + b1v[n]);
        *(unsigned short*)(smem + row*512 + ((col*2) ^ ((row & 7) << 4))) = f2bf(v);
      }
    }
  }
  __syncthreads();   // H1 ready

  // ---- GEMM2: 64x128, K=256; per wave N=16 (acc[4]); ring-4, 3 ahead ----
  int baseH[4][2];
  #pragma unroll
  for (int m = 0; m < 4; ++m){
    int row = m*16 + l15;
    int sw  = (row & 7) << 4;
    int bse = row*512 + ((g4*16) ^ (sw & 0x30));
    int kx  = (row >> 2) & 1;
    baseH[m][0] = bse + ((0 ^ kx) << 6);
    baseH[m][1] = bse + ((1 ^ kx) << 6);
  }
  f32x4 acc2[4] = {};
  #pragma unroll
  for (int g = 0; g < 8; ++g){
    if (g < 5)
      b2raw[(g+3)&3] = *(const u32x4*)(W2f + (size_t)((((g+3)*8 + wave)*64 + lane)*8));
    bf16x8 a[4];
    #pragma unroll
    for (int m = 0; m < 4; ++m)
      a[m] = *(const bf16x8*)(smem + baseH[m][g & 1] + (g >> 1)*128);
    #pragma unroll
    for (int m = 0; m < 4; ++m)
      acc2[m] = __builtin_amdgcn_mfma_f32_16x16x32_bf16(a[m], as_bf(b2raw[g & 3]), acc2[m], 0, 0, 0);
  }

  // W3 fragment prefetch (covered by epilogue-2 VALU)
  u32x4 b3raw[4];
  #pragma unroll
  for (int ks = 0; ks < 4; ++ks)
    b3raw[ks] = *(const u32x4*)(W3f + (size_t)((ks*64 + lane)*8));

  // ---- epilogue 2: bias + GELU -> H2 bf16 swizzled at smem[32K:48K] ----
  #pragma unroll
  for (int m = 0; m < 4; ++m){
    #pragma unroll
    for (int r = 0; r < 4; ++r){
      int row = m*16 + g4*4 + r;
      int col = wave*16 + l15;
      float v = gelu_fast(acc2[m][r] + b2v);
      *(unsigned short*)(smem + OFF_H2 + row*256 + ((col*2) ^ ((row & 7) << 4))) = f2bf(v);
    }
  }
  __syncthreads();   // H2 ready

  // ---- GEMM3: 64x16, K=128; waves 0..3 own rows 16w..16w+15 ----
  if (wave < 4){
    int baseG[2];
    {
      int row = wave*16 + l15;
      int sw  = (row & 7) << 4;
      int bse = OFF_H2 + row*256 + ((g4*16) ^ (sw & 0x30));
      int kx  = (row >> 2) & 1;
      baseG[0] = bse + ((0 ^ kx) << 6);
      baseG[1] = bse + ((1 ^ kx) << 6);
    }
    f32x4 acc3 = {};
    #pragma unroll
    for (int ks = 0; ks < 4; ++ks){
      bf16x8 a = *(const bf16x8*)(smem + baseG[ks & 1] + (ks >> 1)*128);
      acc3 = __builtin_amdgcn_mfma_f32_16x16x32_bf16(a, as_bf(b3raw[ks]), acc3, 0, 0, 0);
    }
    #pragma unroll
    for (int r = 0; r < 4; ++r){
      int grow = row0 + wave*16 + g4*4 + r;
      out2[(size_t)grow*16 + l15] = acc3[r] + b3v;
    }
  }
}

// ---------------- fallback path (ws too small): naive MLP + standalone LN ----------------
__global__ __launch_bounds__(256) void ln_kernel(
    const float* __restrict__ x, const int* __restrict__ groups,
    const float* __restrict__ gammas, const float* __restrict__ betas,
    float* __restrict__ out){
  int row  = blockIdx.x * 4 + (threadIdx.x >> 6);
  int lane = threadIdx.x & 63;
  const float4* xr = (const float4*)(x + (size_t)row * 512);
  float4 a = xr[lane];
  float4 b = xr[lane + 64];
  float s = a.x + a.y + a.z + a.w + b.x + b.y + b.z + b.w;
  float q = a.x*a.x + a.y*a.y + a.z*a.z + a.w*a.w
          + b.x*b.x + b.y*b.y + b.z*b.z + b.w*b.w;
  #pragma unroll
  for (int o = 32; o > 0; o >>= 1){
    s += __shfl_xor(s, o);
    q += __shfl_xor(q, o);
  }
  float mu  = s * (1.0f/512.0f);
  float var = q * (1.0f/512.0f) - mu*mu;
  float rsq = rsqrtf(var + 1e-5f);
  int gi = groups[row];
  int idx = ((unsigned)gi < (unsigned)NSUB) ? gi : NSUB;
  const float4* gr = (const float4*)(gammas + (size_t)idx * 512);
  const float4* br = (const float4*)(betas  + (size_t)idx * 512);
  float4 g0 = gr[lane], g1 = gr[lane + 64];
  float4 e0 = br[lane], e1 = br[lane + 64];
  float4 o0, o1;
  o0.x = (a.x - mu)*rsq*g0.x + e0.x; o0.y = (a.y - mu)*rsq*g0.y + e0.y;
  o0.z = (a.z - mu)*rsq*g0.z + e0.z; o0.w = (a.w - mu)*rsq*g0.w + e0.w;
  o1.x = (b.x - mu)*rsq*g1.x + e1.x; o1.y = (b.y - mu)*rsq*g1.y + e1.y;
  o1.z = (b.z - mu)*rsq*g1.z + e1.z; o1.w = (b.w - mu)*rsq*g1.w + e1.w;
  float4* orow = (float4*)(out + (size_t)row * 512);
  orow[lane]      = o0;
  orow[lane + 64] = o1;
}

__global__ __launch_bounds__(256) void mlp_naive(
    const float* __restrict__ x,
    const float* __restrict__ W1, const float* __restrict__ b1,
    const float* __restrict__ W2, const float* __restrict__ b2,
    const float* __restrict__ W3, const float* __restrict__ b3,
    float* __restrict__ out2){
  __shared__ float xr[512];
  __shared__ float h1[256];
  __shared__ float h2[128];
  int row = blockIdx.x, t = threadIdx.x;
  xr[t]       = x[(size_t)row*512 + t];
  xr[t + 256] = x[(size_t)row*512 + t + 256];
  __syncthreads();
  {
    float s = 0.f;
    for (int k = 0; k < 512; ++k) s += xr[k] * W1[k*256 + t];
    h1[t] = gelu_exact(s + b1[t]);
  }
  __syncthreads();
  if (t < 128){
    float s = 0.f;
    for (int k = 0; k < 256; ++k) s += h1[k] * W2[k*128 + t];
    h2[t] = gelu_exact(s + b2[t]);
  }
  __syncthreads();
  if (t < 16){
    float s = 0.f;
    for (int k = 0; k < 128; ++k) s += h2[k] * W3[k*16 + t];
    out2[(size_t)row*16 + t] = s + b3[t];
  }
}

extern "C" void kernel_launch(void* const* d_in, const int* in_sizes, int n_in,
                              void* d_out, int out_size, void* d_ws, size_t ws_size,
                              hipStream_t stream){
  const float* x      = (const float*)d_in[0];
  const int*   groups = (const int*)d_in[1];
  const float* gammas = (const float*)d_in[2];
  const float* betas  = (const float*)d_in[3];
  const float* W1 = (const float*)d_in[4];
  const float* b1 = (const float*)d_in[5];
  const float* W2 = (const float*)d_in[6];
  const float* b2 = (const float*)d_in[7];
  const float* W3 = (const float*)d_in[8];
  const float* b3 = (const float*)d_in[9];
  float* out  = (float*)d_out;
  const int B = in_sizes[0] / 512;
  float* out2 = out + (size_t)B * 512;

  const int n_u16 = 131072 + 32768 + 2048;
  const size_t ws_need = (size_t)n_u16 * sizeof(unsigned short);
  if (ws_size >= ws_need){
    unsigned short* W1f = (unsigned short*)d_ws;
    unsigned short* W2f = W1f + 131072;
    unsigned short* W3f = W2f + 32768;
    wconv_kernel<<<(n_u16 + 255)/256, 256, 0, stream>>>(W1, W2, W3, W1f, W2f, W3f);
    fused_kernel<<<B/64, 512, 0, stream>>>(x, groups, gammas, betas,
                                           W1f, b1, W2f, b2, W3f, b3, out, out2);
  } else {
    mlp_naive<<<B, 256, 0, stream>>>(x, W1, b1, W2, b2, W3, b3, out2);
    ln_kernel<<<B/4, 256, 0, stream>>>(x, groups, gammas, betas, out);
  }
}